// Round 2
// baseline (935.744 us; speedup 1.0000x reference)
//
#include <hip/hip_runtime.h>
#include <hip/hip_bf16.h>

typedef unsigned short u16;
typedef __attribute__((ext_vector_type(8))) short bf16x8;
typedef __attribute__((ext_vector_type(4))) float f32x4;

#define B_ 8
#define C_ 1024
#define T_ 2048
#define S_ 2048
#define E_ 1024

__device__ __forceinline__ u16 f2bf(float v) {
    __hip_bfloat16 h = __float2bfloat16(v);
    return *reinterpret_cast<u16*>(&h);
}
__device__ __forceinline__ float bf2f(u16 u) {
    __hip_bfloat16 h = *reinterpret_cast<__hip_bfloat16*>(&u);
    return __bfloat162float(h);
}
__device__ __forceinline__ void split2(float v, u16& h, u16& l) {
    h = f2bf(v);
    l = f2bf(v - bf2f(h));
}

// async global->LDS, 16B per lane. LDS ptr must be wave-uniform (HW adds lane*16).
__device__ __forceinline__ void async16(const u16* g, u16* l) {
    __builtin_amdgcn_global_load_lds((const __attribute__((address_space(1))) void*)g,
                                     (__attribute__((address_space(3))) void*)l, 16, 0, 0);
}

// ---------------------------------------------------------------------------
// GEMM: C[m,n] = sum_k A[m,k]*B[n,k]  (both operands row-major over K)
// 128x128 tile, BK=32, 4 waves (2x2), 16x16x32 bf16 MFMA, global_load_lds.
// SPLIT3: A/B given as hi+lo bf16 pairs; acc = hi*hi + hi*lo + lo*hi (bf16x3),
//         issued as three m-sweeps so dependent MFMAs on one acc are 4 apart.
// XOR swizzle (involution slot ^= (row>>1)&3) applied on the *global source*
// during staging and on the ds_read side -> 2 lanes/bank (free per m136).
// EPI: 0 = Q-split epilogue ((acc+bias[n]+x)*scale -> hi/lo bf16)
//      1 = fp32 out (energy)
//      2 = bf16 out (attended_emb)
//      3 = fp32 out + bias[row] + add (residual, [C,T] layout)
// ---------------------------------------------------------------------------
template<int EPI, bool SPLIT3>
__global__ __launch_bounds__(256, 2) void gemm_bt(
    const u16* __restrict__ Ahi, const u16* __restrict__ Alo,
    const u16* __restrict__ Bhi, const u16* __restrict__ Blo,
    int Kdim, long sA, long sB, int N,
    float* __restrict__ outF, long sOutF,
    u16* __restrict__ outB, u16* __restrict__ outB2, long sOutB,
    const float* __restrict__ bias,
    const float* __restrict__ add, long sAdd,
    const float* __restrict__ scale_ptr)
{
    __shared__ u16 smem[(SPLIT3 ? 4 : 2) * 4096];
    u16* As_hi = smem;
    u16* Bs_hi = smem + 4096;
    u16* As_lo = SPLIT3 ? (smem + 8192)  : smem;
    u16* Bs_lo = SPLIT3 ? (smem + 12288) : smem;

    const int b  = blockIdx.z;
    const int bm = blockIdx.y * 128;
    const int bn = blockIdx.x * 128;
    const u16* Ah = Ahi + (size_t)b * sA;
    const u16* Bh = Bhi + (size_t)b * sB;
    const u16* Al = SPLIT3 ? (Alo + (size_t)b * sA) : nullptr;
    const u16* Bl = SPLIT3 ? (Blo + (size_t)b * sB) : nullptr;

    const int tid  = threadIdx.x;
    const int w    = tid >> 6, lane = tid & 63;
    const int wr   = w >> 1,   wc   = w & 1;
    const int lr   = lane & 15, ls  = lane >> 4;

    // staging geometry: chunk = 16 rows x 64B; wave w stages chunks {w, w+4} of each tile
    const int srow  = lane >> 2;
    const int sslot = lane & 3;
    const int kk    = ((sslot ^ ((srow >> 1) & 3)) << 3);   // pre-swizzled global k-offset
    const size_t gA0 = (size_t)(bm + w * 16 + srow) * Kdim + kk;
    const size_t gA1 = (size_t)(bm + (w + 4) * 16 + srow) * Kdim + kk;
    const size_t gB0 = (size_t)(bn + w * 16 + srow) * Kdim + kk;
    const size_t gB1 = (size_t)(bn + (w + 4) * 16 + srow) * Kdim + kk;
    const int l0 = w * 512, l1 = (w + 4) * 512;

    f32x4 acc[4][4];
    #pragma unroll
    for (int m = 0; m < 4; m++) {
        #pragma unroll
        for (int n = 0; n < 4; n++) {
            f32x4 z = {0.f, 0.f, 0.f, 0.f};
            acc[m][n] = z;
        }
    }

    // fragment-read swizzled slot offset (row%16 == lr within each 16-row frag)
    const int foff = ((ls ^ ((lr >> 1) & 3)) << 3);

    for (int k0 = 0; k0 < Kdim; k0 += 32) {
        async16(Ah + gA0 + k0, As_hi + l0);
        async16(Ah + gA1 + k0, As_hi + l1);
        async16(Bh + gB0 + k0, Bs_hi + l0);
        async16(Bh + gB1 + k0, Bs_hi + l1);
        if constexpr (SPLIT3) {
            async16(Al + gA0 + k0, As_lo + l0);
            async16(Al + gA1 + k0, As_lo + l1);
            async16(Bl + gB0 + k0, Bs_lo + l0);
            async16(Bl + gB1 + k0, Bs_lo + l1);
        }
        asm volatile("s_waitcnt vmcnt(0)" ::: "memory");
        __syncthreads();

        bf16x8 ah[4], al[4];
        #pragma unroll
        for (int m = 0; m < 4; m++) {
            int off = (wr * 64 + m * 16 + lr) * 32 + foff;
            ah[m] = *(const bf16x8*)(As_hi + off);
            if constexpr (SPLIT3) al[m] = *(const bf16x8*)(As_lo + off);
        }
        #pragma unroll
        for (int n = 0; n < 4; n++) {
            int off = (wc * 64 + n * 16 + lr) * 32 + foff;
            bf16x8 bh = *(const bf16x8*)(Bs_hi + off);
            if constexpr (SPLIT3) {
                bf16x8 bl = *(const bf16x8*)(Bs_lo + off);
                #pragma unroll
                for (int m = 0; m < 4; m++)
                    acc[m][n] = __builtin_amdgcn_mfma_f32_16x16x32_bf16(ah[m], bh, acc[m][n], 0, 0, 0);
                #pragma unroll
                for (int m = 0; m < 4; m++)
                    acc[m][n] = __builtin_amdgcn_mfma_f32_16x16x32_bf16(ah[m], bl, acc[m][n], 0, 0, 0);
                #pragma unroll
                for (int m = 0; m < 4; m++)
                    acc[m][n] = __builtin_amdgcn_mfma_f32_16x16x32_bf16(al[m], bh, acc[m][n], 0, 0, 0);
            } else {
                #pragma unroll
                for (int m = 0; m < 4; m++)
                    acc[m][n] = __builtin_amdgcn_mfma_f32_16x16x32_bf16(ah[m], bh, acc[m][n], 0, 0, 0);
            }
        }
        __syncthreads();
    }

    float scl = 1.0f;
    if constexpr (EPI == 0) scl = *scale_ptr;

    // C/D layout (verified m89/m91): col = lane&15, row = (lane>>4)*4 + reg
    #pragma unroll
    for (int m = 0; m < 4; m++) {
        #pragma unroll
        for (int n = 0; n < 4; n++) {
            const int Rb = bm + wr * 64 + m * 16 + ls * 4;
            const int Cc = bn + wc * 64 + n * 16 + lr;
            f32x4 v = acc[m][n];
            #pragma unroll
            for (int j = 0; j < 4; j++) {
                const int R = Rb + j;
                const size_t o = (size_t)R * N + Cc;
                float val = v[j];
                if constexpr (EPI == 0) {
                    val = (val + bias[Cc] + add[(size_t)b * sAdd + o]) * scl;
                    u16 h, l;
                    split2(val, h, l);
                    outB[(size_t)b * sOutB + o]  = h;
                    outB2[(size_t)b * sOutB + o] = l;
                } else if constexpr (EPI == 1) {
                    outF[(size_t)b * sOutF + o] = val;
                } else if constexpr (EPI == 2) {
                    outB[(size_t)b * sOutB + o] = f2bf(val);
                } else {
                    outF[(size_t)b * sOutF + o] = val + bias[R] + add[(size_t)b * sAdd + o];
                }
            }
        }
    }
}

// ---------------------------------------------------------------------------
// Prep kernels
// ---------------------------------------------------------------------------

// elementwise fp32 -> bf16 hi (and lo if SPLIT), float4-vectorized
template<bool SPLIT>
__global__ __launch_bounds__(256) void split_cast_kernel(
    const float* __restrict__ in, u16* __restrict__ hi, u16* __restrict__ lo, long n4)
{
    long i = (long)blockIdx.x * blockDim.x + threadIdx.x;
    long stride = (long)gridDim.x * blockDim.x;
    const float4* in4 = (const float4*)in;
    ushort4* h4 = (ushort4*)hi;
    ushort4* l4 = (ushort4*)lo;
    for (; i < n4; i += stride) {
        float4 v = in4[i];
        ushort4 h, l;
        split2(v.x, h.x, l.x);
        split2(v.y, h.y, l.y);
        split2(v.z, h.z, l.z);
        split2(v.w, h.w, l.w);
        h4[i] = h;
        if constexpr (SPLIT) l4[i] = l;
    }
}

// [R,Cc] fp32 -> transposed [Cc,R] bf16 hi(/lo), LDS-tiled 32x32 (pad +1)
template<bool SPLIT>
__global__ __launch_bounds__(256) void transpose_split_kernel(
    const float* __restrict__ in, u16* __restrict__ hi, u16* __restrict__ lo, int R, int Cc)
{
    __shared__ float tile[32][33];
    const size_t boff = (size_t)blockIdx.z * R * Cc;
    const int c0 = blockIdx.x * 32;   // along Cc
    const int r0 = blockIdx.y * 32;   // along R
    const int tx = threadIdx.x, ty = threadIdx.y;
    #pragma unroll
    for (int i = ty; i < 32; i += 8)
        tile[i][tx] = in[boff + (size_t)(r0 + i) * Cc + c0 + tx];
    __syncthreads();
    #pragma unroll
    for (int i = ty; i < 32; i += 8) {
        float v = tile[tx][i];
        size_t o = boff + (size_t)(c0 + i) * R + r0 + tx;
        u16 h, l;
        split2(v, h, l);
        hi[o] = h;
        if constexpr (SPLIT) lo[o] = l;
    }
}

__device__ __forceinline__ float wred_max(float v) {
    #pragma unroll
    for (int off = 32; off; off >>= 1) v = fmaxf(v, __shfl_xor(v, off, 64));
    return v;
}
__device__ __forceinline__ float wred_sum(float v) {
    #pragma unroll
    for (int off = 32; off; off >>= 1) v += __shfl_xor(v, off, 64);
    return v;
}

// row softmax over S=2048, one 256-thread block per row; in-place fp32 + bf16 copy
__global__ __launch_bounds__(256) void softmax_kernel(float* __restrict__ att, u16* __restrict__ attB)
{
    __shared__ float red[4];
    const size_t row = blockIdx.x;
    float* p  = att  + row * (size_t)S_;
    u16*   pb = attB + row * (size_t)S_;
    const int t = threadIdx.x, w = t >> 6, lane = t & 63;

    float4 v0 = ((const float4*)p)[t];
    float4 v1 = ((const float4*)p)[t + 256];
    float m = fmaxf(fmaxf(fmaxf(v0.x, v0.y), fmaxf(v0.z, v0.w)),
                    fmaxf(fmaxf(v1.x, v1.y), fmaxf(v1.z, v1.w)));
    m = wred_max(m);
    if (lane == 0) red[w] = m;
    __syncthreads();
    m = fmaxf(fmaxf(red[0], red[1]), fmaxf(red[2], red[3]));
    __syncthreads();

    float e0 = __expf(v0.x - m), e1 = __expf(v0.y - m), e2 = __expf(v0.z - m), e3 = __expf(v0.w - m);
    float e4 = __expf(v1.x - m), e5 = __expf(v1.y - m), e6 = __expf(v1.z - m), e7 = __expf(v1.w - m);
    float s = ((e0 + e1) + (e2 + e3)) + ((e4 + e5) + (e6 + e7));
    s = wred_sum(s);
    if (lane == 0) red[w] = s;
    __syncthreads();
    s = (red[0] + red[1]) + (red[2] + red[3]);
    const float inv = 1.0f / s;

    float4 o0 = {e0 * inv, e1 * inv, e2 * inv, e3 * inv};
    float4 o1 = {e4 * inv, e5 * inv, e6 * inv, e7 * inv};
    ((float4*)p)[t]       = o0;
    ((float4*)p)[t + 256] = o1;
    ushort4 b0, b1;
    b0.x = f2bf(o0.x); b0.y = f2bf(o0.y); b0.z = f2bf(o0.z); b0.w = f2bf(o0.w);
    b1.x = f2bf(o1.x); b1.y = f2bf(o1.y); b1.z = f2bf(o1.z); b1.w = f2bf(o1.w);
    ((ushort4*)pb)[t]       = b0;
    ((ushort4*)pb)[t + 256] = b1;
}

// ---------------------------------------------------------------------------
extern "C" void kernel_launch(void* const* d_in, const int* in_sizes, int n_in,
                              void* d_out, int out_size, void* d_ws, size_t ws_size,
                              hipStream_t stream)
{
    (void)in_sizes; (void)n_in; (void)out_size; (void)ws_size;
    const float* conved = (const float*)d_in[0];   // [B,C,T]
    const float* encK   = (const float*)d_in[1];   // [B,S,E]
    const float* encV   = (const float*)d_in[2];   // [B,S,E]
    const float* x      = (const float*)d_in[3];   // [B,T,E]
    const float* scale  = (const float*)d_in[4];   // [1]
    const float* W_h2e  = (const float*)d_in[5];   // [E,C]
    const float* b_h2e  = (const float*)d_in[6];   // [E]
    const float* W_e2h  = (const float*)d_in[7];   // [C,E]
    const float* b_e2h  = (const float*)d_in[8];   // [C]

    float* attn = (float*)d_out;                       // [B,T,S]
    float* out2 = attn + (size_t)B_ * T_ * S_;         // [B,C,T]

    const size_t NBT = (size_t)B_ * T_ * E_;  // 16.78M elems (== B*S*E == B*T*C == B*E*S)
    char* p = (char*)d_ws;
    auto take = [&](size_t bytes) { char* r = p; p += bytes; return (u16*)r; };

    // lifetimes: CT/W -> G1 -> Q; Q/K -> G2; attnB/Vt -> G3 -> Aemb; Aemb/We2h -> G4
    u16* Qhi  = take(NBT * 2);
    u16* Qlo  = take(NBT * 2);
    u16* Khi  = take(NBT * 2);
    u16* Klo  = take(NBT * 2);
    u16* Vt   = take(NBT * 2);              // [B,E,S] bf16
    u16* Whi  = take((size_t)E_ * C_ * 2);
    u16* Wlo  = take((size_t)E_ * C_ * 2);
    u16* We2h = take((size_t)C_ * E_ * 2);
    u16* CThi = take(NBT * 2);              // conved^T hi  [B,T,C]
    u16* CTlo = take(NBT * 2);              // conved^T lo
    u16* attnB = CThi;                      // alias: CT dead after G1; attnB spans CThi+CTlo
    u16* Aemb  = Qhi;                       // alias: Q dead after G2; [B,T,E] bf16

    dim3 blk256(256);
    dim3 tblk(32, 8);

    // prep
    transpose_split_kernel<true ><<<dim3(T_ / 32, C_ / 32, B_), tblk, 0, stream>>>(conved, CThi, CTlo, C_, T_);
    split_cast_kernel<true >     <<<dim3(512),  blk256, 0, stream>>>(W_h2e, Whi, Wlo, (long)E_ * C_ / 4);
    split_cast_kernel<true >     <<<dim3(2048), blk256, 0, stream>>>(encK, Khi, Klo, (long)B_ * S_ * E_ / 4);
    transpose_split_kernel<false><<<dim3(E_ / 32, S_ / 32, B_), tblk, 0, stream>>>(encV, Vt, nullptr, S_, E_);
    split_cast_kernel<false>     <<<dim3(512),  blk256, 0, stream>>>(W_e2h, We2h, nullptr, (long)C_ * E_ / 4);

    // 1) Q = (conved^T @ W_h2e^T + b_h2e + x) * scale   [bf16x3] -> Qhi/Qlo
    gemm_bt<0, true><<<dim3(E_ / 128, T_ / 128, B_), blk256, 0, stream>>>(
        CThi, CTlo, Whi, Wlo, C_, (long)T_ * C_, 0L, E_,
        nullptr, 0L, Qhi, Qlo, (long)T_ * E_, b_h2e, x, (long)T_ * E_, scale);

    // 2) energy = Q @ K^T   [bf16x3] -> fp32 into d_out (attention slot)
    gemm_bt<1, true><<<dim3(S_ / 128, T_ / 128, B_), blk256, 0, stream>>>(
        Qhi, Qlo, Khi, Klo, E_, (long)T_ * E_, (long)S_ * E_, S_,
        attn, (long)T_ * S_, nullptr, nullptr, 0L, nullptr, nullptr, 0L, nullptr);

    // 3) softmax rows (in-place fp32) + bf16 copy
    softmax_kernel<<<dim3(B_ * T_), blk256, 0, stream>>>(attn, attnB);

    // 4) attended_emb = attention @ V   (plain bf16) -> Aemb (aliases Qhi)
    gemm_bt<2, false><<<dim3(E_ / 128, T_ / 128, B_), blk256, 0, stream>>>(
        attnB, nullptr, Vt, nullptr, S_, (long)T_ * S_, (long)E_ * S_, E_,
        nullptr, 0L, Aemb, nullptr, (long)T_ * E_, nullptr, nullptr, 0L, nullptr);

    // 5) out2[b,c,t] = conved[b,c,t] + (W_e2h @ attended_emb^T)[c,t] + b_e2h[c]
    gemm_bt<3, false><<<dim3(T_ / 128, C_ / 128, B_), blk256, 0, stream>>>(
        We2h, nullptr, Aemb, nullptr, E_, 0L, (long)T_ * E_, T_,
        out2, (long)C_ * T_, nullptr, nullptr, 0L, b_e2h, conved, (long)C_ * T_, nullptr);
}

// Round 6
// 917.595 us; speedup vs baseline: 1.0198x; 1.0198x over previous
//
#include <hip/hip_runtime.h>
#include <hip/hip_bf16.h>

typedef unsigned short u16;
typedef __attribute__((ext_vector_type(8))) short bf16x8;
typedef __attribute__((ext_vector_type(4))) float f32x4;

#define B_ 8
#define C_ 1024
#define T_ 2048
#define S_ 2048
#define E_ 1024

__device__ __forceinline__ u16 f2bf(float v) {
    __hip_bfloat16 h = __float2bfloat16(v);
    return *reinterpret_cast<u16*>(&h);
}
__device__ __forceinline__ float bf2f(u16 u) {
    __hip_bfloat16 h = *reinterpret_cast<__hip_bfloat16*>(&u);
    return __bfloat162float(h);
}
__device__ __forceinline__ void split2(float v, u16& h, u16& l) {
    h = f2bf(v);
    l = f2bf(v - bf2f(h));
}

// async global->LDS, 16B per lane. LDS ptr must be wave-uniform (HW adds lane*16).
__device__ __forceinline__ void async16(const u16* g, u16* l) {
    __builtin_amdgcn_global_load_lds((const __attribute__((address_space(1))) void*)g,
                                     (__attribute__((address_space(3))) void*)l, 16, 0, 0);
}

// ---------------------------------------------------------------------------
// GEMM: C[m,n] = sum_k A[m,k]*B[n,k]  (both operands row-major over K)
// 128x128 tile, BK=32, 4 waves (2x2), 16x16x32 bf16 MFMA, global_load_lds.
// launch_bounds(256,4): VGPR=68 fits 4 waves/EU easily; 32KB LDS -> 4 blk/CU
// (was 2) so resident-block overlap hides the vmcnt(0)+barrier drain (m114).
// XCD-aware bijective block swizzle (m204) for L2 locality.
// SPLIT3: A/B given as hi+lo bf16 pairs; acc = hi*hi + hi*lo + lo*hi (bf16x3).
// XOR swizzle (involution slot ^= (row>>1)&3) on the global source during
// staging and on the ds_read side -> 0 bank conflicts (HW-verified r2).
// EPI: 0 = Q-split epilogue ((acc+bias[n]+x)*scale -> hi/lo bf16)
//      1 = fp32 out (energy)
//      2 = bf16 out (attended_emb)
//      3 = fp32 out + bias[row] + add (residual, [C,T] layout)
// ---------------------------------------------------------------------------
template<int EPI, bool SPLIT3>
__global__ __launch_bounds__(256, 4) void gemm_bt(
    const u16* __restrict__ Ahi, const u16* __restrict__ Alo,
    const u16* __restrict__ Bhi, const u16* __restrict__ Blo,
    int Kdim, long sA, long sB, int N,
    float* __restrict__ outF, long sOutF,
    u16* __restrict__ outB, u16* __restrict__ outB2, long sOutB,
    const float* __restrict__ bias,
    const float* __restrict__ add, long sAdd,
    const float* __restrict__ scale_ptr)
{
    __shared__ u16 smem[(SPLIT3 ? 4 : 2) * 4096];
    u16* As_hi = smem;
    u16* Bs_hi = smem + 4096;
    u16* As_lo = SPLIT3 ? (smem + 8192)  : smem;
    u16* Bs_lo = SPLIT3 ? (smem + 12288) : smem;

    // XCD-aware bijective swizzle of the per-z flat block id (m204).
    const int gx = gridDim.x;
    const int nwg = gx * gridDim.y;
    int f = blockIdx.y * gx + blockIdx.x;
    {
        const int q = nwg >> 3, r = nwg & 7;
        const int xcd = f & 7, idx = f >> 3;
        f = (xcd < r ? xcd * (q + 1) : r * (q + 1) + (xcd - r) * q) + idx;
    }
    const int b  = blockIdx.z;
    const int bm = (f / gx) * 128;
    const int bn = (f % gx) * 128;

    const u16* Ah = Ahi + (size_t)b * sA;
    const u16* Bh = Bhi + (size_t)b * sB;
    const u16* Al = SPLIT3 ? (Alo + (size_t)b * sA) : nullptr;
    const u16* Bl = SPLIT3 ? (Blo + (size_t)b * sB) : nullptr;

    const int tid  = threadIdx.x;
    const int w    = tid >> 6, lane = tid & 63;
    const int wr   = w >> 1,   wc   = w & 1;
    const int lr   = lane & 15, ls  = lane >> 4;

    // staging geometry: chunk = 16 rows x 64B; wave w stages chunks {w, w+4} of each tile
    const int srow  = lane >> 2;
    const int sslot = lane & 3;
    const int kk    = ((sslot ^ ((srow >> 1) & 3)) << 3);   // pre-swizzled global k-offset
    const size_t gA0 = (size_t)(bm + w * 16 + srow) * Kdim + kk;
    const size_t gA1 = (size_t)(bm + (w + 4) * 16 + srow) * Kdim + kk;
    const size_t gB0 = (size_t)(bn + w * 16 + srow) * Kdim + kk;
    const size_t gB1 = (size_t)(bn + (w + 4) * 16 + srow) * Kdim + kk;
    const int l0 = w * 512, l1 = (w + 4) * 512;

    f32x4 acc[4][4];
    #pragma unroll
    for (int m = 0; m < 4; m++) {
        #pragma unroll
        for (int n = 0; n < 4; n++) {
            f32x4 z = {0.f, 0.f, 0.f, 0.f};
            acc[m][n] = z;
        }
    }

    // fragment-read swizzled slot offset (row%16 == lr within each 16-row frag)
    const int foff = ((ls ^ ((lr >> 1) & 3)) << 3);

    for (int k0 = 0; k0 < Kdim; k0 += 32) {
        async16(Ah + gA0 + k0, As_hi + l0);
        async16(Ah + gA1 + k0, As_hi + l1);
        async16(Bh + gB0 + k0, Bs_hi + l0);
        async16(Bh + gB1 + k0, Bs_hi + l1);
        if constexpr (SPLIT3) {
            async16(Al + gA0 + k0, As_lo + l0);
            async16(Al + gA1 + k0, As_lo + l1);
            async16(Bl + gB0 + k0, Bs_lo + l0);
            async16(Bl + gB1 + k0, Bs_lo + l1);
        }
        asm volatile("s_waitcnt vmcnt(0)" ::: "memory");
        __syncthreads();

        bf16x8 ah[4], al[4];
        #pragma unroll
        for (int m = 0; m < 4; m++) {
            int off = (wr * 64 + m * 16 + lr) * 32 + foff;
            ah[m] = *(const bf16x8*)(As_hi + off);
            if constexpr (SPLIT3) al[m] = *(const bf16x8*)(As_lo + off);
        }
        #pragma unroll
        for (int n = 0; n < 4; n++) {
            int off = (wc * 64 + n * 16 + lr) * 32 + foff;
            bf16x8 bh = *(const bf16x8*)(Bs_hi + off);
            if constexpr (SPLIT3) {
                bf16x8 bl = *(const bf16x8*)(Bs_lo + off);
                #pragma unroll
                for (int m = 0; m < 4; m++)
                    acc[m][n] = __builtin_amdgcn_mfma_f32_16x16x32_bf16(ah[m], bh, acc[m][n], 0, 0, 0);
                #pragma unroll
                for (int m = 0; m < 4; m++)
                    acc[m][n] = __builtin_amdgcn_mfma_f32_16x16x32_bf16(ah[m], bl, acc[m][n], 0, 0, 0);
                #pragma unroll
                for (int m = 0; m < 4; m++)
                    acc[m][n] = __builtin_amdgcn_mfma_f32_16x16x32_bf16(al[m], bh, acc[m][n], 0, 0, 0);
            } else {
                #pragma unroll
                for (int m = 0; m < 4; m++)
                    acc[m][n] = __builtin_amdgcn_mfma_f32_16x16x32_bf16(ah[m], bh, acc[m][n], 0, 0, 0);
            }
        }
        __syncthreads();
    }

    float scl = 1.0f;
    if constexpr (EPI == 0) scl = *scale_ptr;

    // C/D layout (verified m89/m91): col = lane&15, row = (lane>>4)*4 + reg
    #pragma unroll
    for (int m = 0; m < 4; m++) {
        #pragma unroll
        for (int n = 0; n < 4; n++) {
            const int Rb = bm + wr * 64 + m * 16 + ls * 4;
            const int Cc = bn + wc * 64 + n * 16 + lr;
            f32x4 v = acc[m][n];
            #pragma unroll
            for (int j = 0; j < 4; j++) {
                const int R = Rb + j;
                const size_t o = (size_t)R * N + Cc;
                float val = v[j];
                if constexpr (EPI == 0) {
                    val = (val + bias[Cc] + add[(size_t)b * sAdd + o]) * scl;
                    u16 h, l;
                    split2(val, h, l);
                    outB[(size_t)b * sOutB + o]  = h;
                    outB2[(size_t)b * sOutB + o] = l;
                } else if constexpr (EPI == 1) {
                    outF[(size_t)b * sOutF + o] = val;
                } else if constexpr (EPI == 2) {
                    outB[(size_t)b * sOutB + o] = f2bf(val);
                } else {
                    outF[(size_t)b * sOutF + o] = val + bias[R] + add[(size_t)b * sAdd + o];
                }
            }
        }
    }
}

// ---------------------------------------------------------------------------
// Prep kernels
// ---------------------------------------------------------------------------

// elementwise fp32 -> bf16 hi (and lo if SPLIT), float4-vectorized
template<bool SPLIT>
__global__ __launch_bounds__(256) void split_cast_kernel(
    const float* __restrict__ in, u16* __restrict__ hi, u16* __restrict__ lo, long n4)
{
    long i = (long)blockIdx.x * blockDim.x + threadIdx.x;
    long stride = (long)gridDim.x * blockDim.x;
    const float4* in4 = (const float4*)in;
    ushort4* h4 = (ushort4*)hi;
    ushort4* l4 = (ushort4*)lo;
    for (; i < n4; i += stride) {
        float4 v = in4[i];
        ushort4 h, l;
        split2(v.x, h.x, l.x);
        split2(v.y, h.y, l.y);
        split2(v.z, h.z, l.z);
        split2(v.w, h.w, l.w);
        h4[i] = h;
        if constexpr (SPLIT) l4[i] = l;
    }
}

// [R,Cc] fp32 -> transposed [Cc,R] bf16 hi(/lo). 32x32 tile; block (8,32).
// Read: float4 per thread (row r0+ty, cols c0+4tx..+3) -> coalesced 16B.
// Write: ushort4 per thread (out row c0+ty, cols r0+4tx..+3) -> coalesced 8B.
// LDS banks <=2-way on both phases (pad 33; addr algebra checked).
template<bool SPLIT>
__global__ __launch_bounds__(256) void transpose_split_kernel(
    const float* __restrict__ in, u16* __restrict__ hi, u16* __restrict__ lo, int R, int Cc)
{
    __shared__ float tile[32][33];
    const size_t boff = (size_t)blockIdx.z * R * Cc;
    const int c0 = blockIdx.x * 32;   // along Cc
    const int r0 = blockIdx.y * 32;   // along R
    const int tx = threadIdx.x;       // 0..7
    const int ty = threadIdx.y;       // 0..31

    float4 v = *(const float4*)&in[boff + (size_t)(r0 + ty) * Cc + c0 + 4 * tx];
    tile[ty][4 * tx + 0] = v.x;
    tile[ty][4 * tx + 1] = v.y;
    tile[ty][4 * tx + 2] = v.z;
    tile[ty][4 * tx + 3] = v.w;
    __syncthreads();

    ushort4 h, l;
    split2(tile[4 * tx + 0][ty], h.x, l.x);
    split2(tile[4 * tx + 1][ty], h.y, l.y);
    split2(tile[4 * tx + 2][ty], h.z, l.z);
    split2(tile[4 * tx + 3][ty], h.w, l.w);
    const size_t o = boff + (size_t)(c0 + ty) * R + r0 + 4 * tx;
    *(ushort4*)&hi[o] = h;
    if constexpr (SPLIT) *(ushort4*)&lo[o] = l;
}

__device__ __forceinline__ float wred_max(float v) {
    #pragma unroll
    for (int off = 32; off; off >>= 1) v = fmaxf(v, __shfl_xor(v, off, 64));
    return v;
}
__device__ __forceinline__ float wred_sum(float v) {
    #pragma unroll
    for (int off = 32; off; off >>= 1) v += __shfl_xor(v, off, 64);
    return v;
}

// row softmax over S=2048, one 256-thread block per row; in-place fp32 + bf16 copy
__global__ __launch_bounds__(256) void softmax_kernel(float* __restrict__ att, u16* __restrict__ attB)
{
    __shared__ float red[4];
    const size_t row = blockIdx.x;
    float* p  = att  + row * (size_t)S_;
    u16*   pb = attB + row * (size_t)S_;
    const int t = threadIdx.x, w = t >> 6, lane = t & 63;

    float4 v0 = ((const float4*)p)[t];
    float4 v1 = ((const float4*)p)[t + 256];
    float m = fmaxf(fmaxf(fmaxf(v0.x, v0.y), fmaxf(v0.z, v0.w)),
                    fmaxf(fmaxf(v1.x, v1.y), fmaxf(v1.z, v1.w)));
    m = wred_max(m);
    if (lane == 0) red[w] = m;
    __syncthreads();
    m = fmaxf(fmaxf(red[0], red[1]), fmaxf(red[2], red[3]));
    __syncthreads();

    float e0 = __expf(v0.x - m), e1 = __expf(v0.y - m), e2 = __expf(v0.z - m), e3 = __expf(v0.w - m);
    float e4 = __expf(v1.x - m), e5 = __expf(v1.y - m), e6 = __expf(v1.z - m), e7 = __expf(v1.w - m);
    float s = ((e0 + e1) + (e2 + e3)) + ((e4 + e5) + (e6 + e7));
    s = wred_sum(s);
    if (lane == 0) red[w] = s;
    __syncthreads();
    s = (red[0] + red[1]) + (red[2] + red[3]);
    const float inv = 1.0f / s;

    float4 o0 = {e0 * inv, e1 * inv, e2 * inv, e3 * inv};
    float4 o1 = {e4 * inv, e5 * inv, e6 * inv, e7 * inv};
    ((float4*)p)[t]       = o0;
    ((float4*)p)[t + 256] = o1;
    ushort4 b0, b1;
    b0.x = f2bf(o0.x); b0.y = f2bf(o0.y); b0.z = f2bf(o0.z); b0.w = f2bf(o0.w);
    b1.x = f2bf(o1.x); b1.y = f2bf(o1.y); b1.z = f2bf(o1.z); b1.w = f2bf(o1.w);
    ((ushort4*)pb)[t]       = b0;
    ((ushort4*)pb)[t + 256] = b1;
}

// ---------------------------------------------------------------------------
extern "C" void kernel_launch(void* const* d_in, const int* in_sizes, int n_in,
                              void* d_out, int out_size, void* d_ws, size_t ws_size,
                              hipStream_t stream)
{
    (void)in_sizes; (void)n_in; (void)out_size; (void)ws_size;
    const float* conved = (const float*)d_in[0];   // [B,C,T]
    const float* encK   = (const float*)d_in[1];   // [B,S,E]
    const float* encV   = (const float*)d_in[2];   // [B,S,E]
    const float* x      = (const float*)d_in[3];   // [B,T,E]
    const float* scale  = (const float*)d_in[4];   // [1]
    const float* W_h2e  = (const float*)d_in[5];   // [E,C]
    const float* b_h2e  = (const float*)d_in[6];   // [E]
    const float* W_e2h  = (const float*)d_in[7];   // [C,E]
    const float* b_e2h  = (const float*)d_in[8];   // [C]

    float* attn = (float*)d_out;                       // [B,T,S]
    float* out2 = attn + (size_t)B_ * T_ * S_;         // [B,C,T]

    const size_t NBT = (size_t)B_ * T_ * E_;  // 16.78M elems (== B*S*E == B*T*C == B*E*S)
    char* p = (char*)d_ws;
    auto take = [&](size_t bytes) { char* r = p; p += bytes; return (u16*)r; };

    // lifetimes: CT/W -> G1 -> Q; Q/K -> G2; attnB/Vt -> G3 -> Aemb; Aemb/We2h -> G4
    u16* Qhi  = take(NBT * 2);
    u16* Qlo  = take(NBT * 2);
    u16* Khi  = take(NBT * 2);
    u16* Klo  = take(NBT * 2);
    u16* Vt   = take(NBT * 2);              // [B,E,S] bf16
    u16* Whi  = take((size_t)E_ * C_ * 2);
    u16* Wlo  = take((size_t)E_ * C_ * 2);
    u16* We2h = take((size_t)C_ * E_ * 2);
    u16* CThi = take(NBT * 2);              // conved^T hi  [B,T,C]
    u16* CTlo = take(NBT * 2);              // conved^T lo
    u16* attnB = CThi;                      // alias: CT dead after G1; attnB spans CThi+CTlo
    u16* Aemb  = Qhi;                       // alias: Q dead after G2; [B,T,E] bf16

    dim3 blk256(256);
    dim3 tblk(8, 32);

    // prep
    transpose_split_kernel<true ><<<dim3(T_ / 32, C_ / 32, B_), tblk, 0, stream>>>(conved, CThi, CTlo, C_, T_);
    split_cast_kernel<true >     <<<dim3(512),  blk256, 0, stream>>>(W_h2e, Whi, Wlo, (long)E_ * C_ / 4);
    split_cast_kernel<true >     <<<dim3(2048), blk256, 0, stream>>>(encK, Khi, Klo, (long)B_ * S_ * E_ / 4);
    transpose_split_kernel<false><<<dim3(E_ / 32, S_ / 32, B_), tblk, 0, stream>>>(encV, Vt, nullptr, S_, E_);
    split_cast_kernel<false>     <<<dim3(512),  blk256, 0, stream>>>(W_e2h, We2h, nullptr, (long)C_ * E_ / 4);

    // 1) Q = (conved^T @ W_h2e^T + b_h2e + x) * scale   [bf16x3] -> Qhi/Qlo
    gemm_bt<0, true><<<dim3(E_ / 128, T_ / 128, B_), blk256, 0, stream>>>(
        CThi, CTlo, Whi, Wlo, C_, (long)T_ * C_, 0L, E_,
        nullptr, 0L, Qhi, Qlo, (long)T_ * E_, b_h2e, x, (long)T_ * E_, scale);

    // 2) energy = Q @ K^T   [bf16x3] -> fp32 into d_out (attention slot)
    gemm_bt<1, true><<<dim3(S_ / 128, T_ / 128, B_), blk256, 0, stream>>>(
        Qhi, Qlo, Khi, Klo, E_, (long)T_ * E_, (long)S_ * E_, S_,
        attn, (long)T_ * S_, nullptr, nullptr, 0L, nullptr, nullptr, 0L, nullptr);

    // 3) softmax rows (in-place fp32) + bf16 copy
    softmax_kernel<<<dim3(B_ * T_), blk256, 0, stream>>>(attn, attnB);

    // 4) attended_emb = attention @ V   (plain bf16) -> Aemb (aliases Qhi)
    gemm_bt<2, false><<<dim3(E_ / 128, T_ / 128, B_), blk256, 0, stream>>>(
        attnB, nullptr, Vt, nullptr, S_, (long)T_ * S_, (long)E_ * S_, E_,
        nullptr, 0L, Aemb, nullptr, (long)T_ * E_, nullptr, nullptr, 0L, nullptr);

    // 5) out2[b,c,t] = conved[b,c,t] + (W_e2h @ attended_emb^T)[c,t] + b_e2h[c]
    gemm_bt<3, false><<<dim3(T_ / 128, C_ / 128, B_), blk256, 0, stream>>>(
        We2h, nullptr, Aemb, nullptr, E_, 0L, (long)T_ * E_, T_,
        out2, (long)C_ * T_, nullptr, nullptr, 0L, b_e2h, conved, (long)C_ * T_, nullptr);
}